// Round 7
// baseline (184.793 us; speedup 1.0000x reference)
//
#include <hip/hip_runtime.h>
#include <hip/hip_bf16.h>
#include <cstdint>
#include <cstddef>

using bf16x8   = __attribute__((ext_vector_type(8))) short;
using f32x4    = __attribute__((ext_vector_type(4))) float;
using f32x16   = __attribute__((ext_vector_type(16))) float;
using ushort8  = __attribute__((ext_vector_type(8))) unsigned short;
using ushort4v = __attribute__((ext_vector_type(4))) unsigned short;
using float4v  = __attribute__((ext_vector_type(4))) float;

#define MFMA16(a,b,c) __builtin_amdgcn_mfma_f32_16x16x32_bf16((a),(b),(c),0,0,0)
#define MFMA32(a,b,c) __builtin_amdgcn_mfma_f32_32x32x16_bf16((a),(b),(c),0,0,0)

#define QSCALE 0.18033688011112042f   // log2(e)/8

__device__ __forceinline__ unsigned short f2bf(float f){
    union { float f; unsigned u; } v; v.f = f;
    unsigned r = v.u + 0x7FFFu + ((v.u >> 16) & 1u);
    return (unsigned short)(r >> 16);
}

__device__ __forceinline__ int cvtpk(float lo, float hi){
    int r;
    asm volatile("v_cvt_pk_bf16_f32 %0, %1, %2" : "=v"(r) : "v"(lo), "v"(hi));
    return r;
}

#if __has_builtin(__builtin_amdgcn_permlane32_swap)
__device__ __forceinline__ void plswap(int &a, int &b){
    auto r = __builtin_amdgcn_permlane32_swap(a, b, false, false);
    a = r[0]; b = r[1];
}
#else
__device__ __forceinline__ void plswap(int &a, int &b){
    int ta = __shfl_xor(a, 32), tb = __shfl_xor(b, 32);
    bool hi = ((threadIdx.x & 63) >= 32);
    int na = hi ? tb : a;
    int nb = hi ? b  : ta;
    a = na; b = nb;
}
#endif

__device__ __forceinline__ void gload16(const unsigned short* g, unsigned short* l){
    __builtin_amdgcn_global_load_lds(
        (const __attribute__((address_space(1))) void*)g,
        (__attribute__((address_space(3))) void*)l,
        16, 0, 0);
}

// ---------------------------------------------------------------- GroupNorm
__global__ __launch_bounds__(256) void gn_stats(const float* __restrict__ x,
                                                float* __restrict__ mean,
                                                float* __restrict__ rstd){
    int bg = blockIdx.x;
    const float4v* p4 = (const float4v*)(x + (size_t)bg * 65536);
    float s = 0.f, ss = 0.f;
    for (int i = threadIdx.x; i < 16384; i += 256){
        float4v v = p4[i];
        s  += v[0]+v[1]+v[2]+v[3];
        ss += v[0]*v[0]+v[1]*v[1]+v[2]*v[2]+v[3]*v[3];
    }
    __shared__ float ls[4], lss[4];
    int lane = threadIdx.x & 63, w = threadIdx.x >> 6;
    #pragma unroll
    for (int o = 32; o > 0; o >>= 1){ s += __shfl_down(s, o); ss += __shfl_down(ss, o); }
    if (lane == 0){ ls[w] = s; lss[w] = ss; }
    __syncthreads();
    if (threadIdx.x == 0){
        float S = ls[0]+ls[1]+ls[2]+ls[3];
        float SS = lss[0]+lss[1]+lss[2]+lss[3];
        float m = S * (1.f/65536.f);
        float var = SS * (1.f/65536.f) - m*m;
        mean[bg] = m;
        rstd[bg] = rsqrtf(var + 1e-5f);
    }
}

__global__ __launch_bounds__(256) void gn_apply(const float* __restrict__ x,
                                                const float* __restrict__ mean,
                                                const float* __restrict__ rstd,
                                                const float* __restrict__ gw,
                                                const float* __restrict__ gb,
                                                unsigned short* __restrict__ xn){
    int b = blockIdx.z, c0 = blockIdx.y * 64, n0 = blockIdx.x * 64;
    __shared__ unsigned short tile[64][68];
    for (int i = threadIdx.x; i < 64*16; i += 256){
        int row = i >> 4, f4 = i & 15;
        int c = c0 + row;
        int g = b*32 + (c >> 4);
        float rs = rstd[g];
        float wgt = gw[c] * rs;
        float bia = gb[c] - mean[g] * wgt;
        float4v v = *(const float4v*)(x + ((size_t)(b*512 + c))*4096 + n0 + f4*4);
        ushort4v o;
        #pragma unroll
        for (int j = 0; j < 4; j++) o[j] = f2bf(v[j]*wgt + bia);
        *(ushort4v*)&tile[row][f4*4] = o;
    }
    __syncthreads();
    for (int i = threadIdx.x; i < 64*8; i += 256){
        int nr = i >> 3, c8 = i & 7;
        ushort8 o;
        #pragma unroll
        for (int j = 0; j < 8; j++) o[j] = tile[c8*8 + j][nr];
        *(ushort8*)(xn + ((size_t)(b*4096 + n0 + nr))*512 + c0 + c8*8) = o;
    }
}

__global__ __launch_bounds__(256) void wconv(const float* __restrict__ w0, const float* __restrict__ w1,
                                             const float* __restrict__ w2, const float* __restrict__ w3,
                                             unsigned short* wqk, unsigned short* wv, unsigned short* wo){
    const float* src; unsigned short* dst; float sc = 1.0f;
    switch (blockIdx.y){
        case 0: src = w0; dst = wqk;          sc = QSCALE; break;
        case 1: src = w1; dst = wqk + 512*512; break;
        case 2: src = w2; dst = wv; break;
        default: src = w3; dst = wo; break;
    }
    int i = (blockIdx.x*256 + threadIdx.x) * 4;
    float4v v = *(const float4v*)(src + i);
    ushort4v o;
    #pragma unroll
    for (int j = 0; j < 4; j++) o[j] = f2bf(v[j]*sc);
    *(ushort4v*)(dst + i) = o;
}

// ---------------------------------------------------------------- fused Q/K projection (m97-style)
__global__ __launch_bounds__(256) void gemm_qk2(const unsigned short* __restrict__ xn,
                                                const unsigned short* __restrict__ wqk,
                                                const float* __restrict__ bq,
                                                const float* __restrict__ bk,
                                                unsigned short* __restrict__ Q,
                                                unsigned short* __restrict__ K){
    __shared__ unsigned short Al[128*32];
    __shared__ unsigned short Bl[128*32];
    int t = threadIdx.x, lane = t & 63, w = t >> 6;
    int wr = w >> 1, wc = w & 1;
    int m0 = blockIdx.x * 128, n0 = blockIdx.y * 128;
    int lr = lane >> 2, lc = lane & 3;
    f32x4 acc[4][4] = {};

    const unsigned short* Asrc = xn  + (size_t)(m0 + w*32 + lr)*512 + lc*8;
    const unsigned short* Bsrc = wqk + (size_t)(n0 + w*32 + lr)*512 + lc*8;
    unsigned short* Adst = &Al[(w*32)*32];
    unsigned short* Bdst = &Bl[(w*32)*32];

    for (int ks = 0; ks < 16; ks++){
        gload16(Asrc + ks*32,          Adst);
        gload16(Asrc + ks*32 + 16*512, Adst + 16*32);
        gload16(Bsrc + ks*32,          Bdst);
        gload16(Bsrc + ks*32 + 16*512, Bdst + 16*32);
        asm volatile("s_waitcnt vmcnt(0)" ::: "memory");
        __syncthreads();
        bf16x8 a[4], b[4];
        #pragma unroll
        for (int mi = 0; mi < 4; mi++) a[mi] = *(bf16x8*)&Al[(wr*64 + mi*16 + (lane&15))*32 + (lane>>4)*8];
        #pragma unroll
        for (int ni = 0; ni < 4; ni++) b[ni] = *(bf16x8*)&Bl[(wc*64 + ni*16 + (lane&15))*32 + (lane>>4)*8];
        #pragma unroll
        for (int mi = 0; mi < 4; mi++)
            #pragma unroll
            for (int ni = 0; ni < 4; ni++)
                acc[mi][ni] = MFMA16(a[mi], b[ni], acc[mi][ni]);
        __syncthreads();
    }

    int cK = n0 >> 9;
    const float* bias = cK ? bk : bq;
    unsigned short* dst0 = cK ? K : Q;
    float bsc = cK ? 1.0f : QSCALE;
    #pragma unroll
    for (int mi = 0; mi < 4; mi++)
        #pragma unroll
        for (int ni = 0; ni < 4; ni++)
            #pragma unroll
            for (int r = 0; r < 4; r++){
                int mrow = m0 + wr*64 + mi*16 + (lane>>4)*4 + r;
                int col  = (n0 & 511) + wc*64 + ni*16 + (lane&15);
                int b_ = mrow >> 12, n = mrow & 4095;
                int h = col >> 6, d = col & 63;
                float v = acc[mi][ni][r] + bias[col]*bsc;
                dst0[(size_t)((b_*8+h)*4096 + n)*64 + d] = f2bf(v);
            }
}

// ---------------------------------------------------------------- V projection (swapped -> Vt, m97-style)
__global__ __launch_bounds__(256) void gemm_v2(const unsigned short* __restrict__ Wv,
                                               const unsigned short* __restrict__ xn,
                                               const float* __restrict__ bv,
                                               unsigned short* __restrict__ Vt){
    __shared__ unsigned short Al[64*32];
    __shared__ unsigned short Bl[128*32];
    int t = threadIdx.x, lane = t & 63, w = t >> 6;
    int wr = w >> 1, wc = w & 1;
    int m0 = blockIdx.x * 64, n0 = blockIdx.y * 128;
    int lr = lane >> 2, lc = lane & 3;
    f32x4 acc[2][4] = {};

    const unsigned short* Asrc = Wv + (size_t)(m0 + w*16 + lr)*512 + lc*8;
    const unsigned short* Bsrc = xn + (size_t)(n0 + w*32 + lr)*512 + lc*8;
    unsigned short* Adst = &Al[(w*16)*32];
    unsigned short* Bdst = &Bl[(w*32)*32];

    for (int ks = 0; ks < 16; ks++){
        gload16(Asrc + ks*32,          Adst);
        gload16(Bsrc + ks*32,          Bdst);
        gload16(Bsrc + ks*32 + 16*512, Bdst + 16*32);
        asm volatile("s_waitcnt vmcnt(0)" ::: "memory");
        __syncthreads();
        bf16x8 a[2], b[4];
        #pragma unroll
        for (int mi = 0; mi < 2; mi++) a[mi] = *(bf16x8*)&Al[(wr*32 + mi*16 + (lane&15))*32 + (lane>>4)*8];
        #pragma unroll
        for (int ni = 0; ni < 4; ni++) b[ni] = *(bf16x8*)&Bl[(wc*64 + ni*16 + (lane&15))*32 + (lane>>4)*8];
        #pragma unroll
        for (int mi = 0; mi < 2; mi++)
            #pragma unroll
            for (int ni = 0; ni < 4; ni++)
                acc[mi][ni] = MFMA16(a[mi], b[ni], acc[mi][ni]);
        __syncthreads();
    }
    #pragma unroll
    for (int mi = 0; mi < 2; mi++)
        #pragma unroll
        for (int ni = 0; ni < 4; ni++)
            #pragma unroll
            for (int r = 0; r < 4; r++){
                int row  = m0 + wr*32 + mi*16 + (lane>>4)*4 + r;
                int colm = n0 + wc*64 + ni*16 + (lane&15);
                int b_ = colm >> 12, n = colm & 4095;
                int h = row >> 6, d = row & 63;
                float v = acc[mi][ni][r] + bv[row];
                Vt[(size_t)((b_*8+h)*64 + d)*4096 + n] = f2bf(v);
            }
}

// ---------------------------------------------------------------- output projection (swapped, m97-style) + residual
__global__ __launch_bounds__(256) void gemm_o2(const unsigned short* __restrict__ Wo,
                                               const unsigned short* __restrict__ Om,
                                               const float* __restrict__ bo,
                                               const float* __restrict__ resid,
                                               float* __restrict__ outp){
    __shared__ unsigned short Al[64*32];
    __shared__ unsigned short Bl[128*32];
    int t = threadIdx.x, lane = t & 63, w = t >> 6;
    int wr = w >> 1, wc = w & 1;
    int m0 = blockIdx.x * 64, n0 = blockIdx.y * 128;
    int lr = lane >> 2, lc = lane & 3;
    f32x4 acc[2][4] = {};

    const unsigned short* Asrc = Wo + (size_t)(m0 + w*16 + lr)*512 + lc*8;
    const unsigned short* Bsrc = Om + (size_t)(n0 + w*32 + lr)*512 + lc*8;
    unsigned short* Adst = &Al[(w*16)*32];
    unsigned short* Bdst = &Bl[(w*32)*32];

    for (int ks = 0; ks < 16; ks++){
        gload16(Asrc + ks*32,          Adst);
        gload16(Bsrc + ks*32,          Bdst);
        gload16(Bsrc + ks*32 + 16*512, Bdst + 16*32);
        asm volatile("s_waitcnt vmcnt(0)" ::: "memory");
        __syncthreads();
        bf16x8 a[2], b[4];
        #pragma unroll
        for (int mi = 0; mi < 2; mi++) a[mi] = *(bf16x8*)&Al[(wr*32 + mi*16 + (lane&15))*32 + (lane>>4)*8];
        #pragma unroll
        for (int ni = 0; ni < 4; ni++) b[ni] = *(bf16x8*)&Bl[(wc*64 + ni*16 + (lane&15))*32 + (lane>>4)*8];
        #pragma unroll
        for (int mi = 0; mi < 2; mi++)
            #pragma unroll
            for (int ni = 0; ni < 4; ni++)
                acc[mi][ni] = MFMA16(a[mi], b[ni], acc[mi][ni]);
        __syncthreads();
    }
    #pragma unroll
    for (int mi = 0; mi < 2; mi++)
        #pragma unroll
        for (int ni = 0; ni < 4; ni++)
            #pragma unroll
            for (int r = 0; r < 4; r++){
                int row  = m0 + wr*32 + mi*16 + (lane>>4)*4 + r;
                int colm = n0 + wc*64 + ni*16 + (lane&15);
                int b_ = colm >> 12, n = colm & 4095;
                size_t oi = ((size_t)(b_*512 + row))*4096 + n;
                outp[oi] = acc[mi][ni][r] + bo[row] + resid[oi];
            }
}

// ---------------------------------------------------------------- flash attention v6
// 2-tile software pipeline: QK(t) MFMAs overlap exp/pack(t-1) VALU + PV(t-1).
// K in LDS (dbuf, gload_lds, swizzled); V fragments loaded global->reg (L2-served)
// with 2-tile latency slack. Counted vmcnt(4). 2 waves kv-split, LDS-merge.
__global__ __launch_bounds__(128, 2) void attn6(const unsigned short* __restrict__ Q,
                                                const unsigned short* __restrict__ K,
                                                const unsigned short* __restrict__ Vt,
                                                unsigned short* __restrict__ O){
    int bid = blockIdx.x;
    int idx = bid >> 3;
    int bh = ((bid & 7) << 1) | (idx >> 6);
    int qt = idx & 63;
    int t_ = threadIdx.x, lane = t_ & 63, w = t_ >> 6;   // w = kv-half
    int ln = lane & 31, hi = lane >> 5;
    int q0 = qt * 64;

    __shared__ unsigned short Kl[2][64*64];   // K dbuf, 16 KB
    __shared__ float mb[4224];                // merge buffer

    const unsigned short* Qb = Q  + (size_t)bh * 4096 * 64;
    const unsigned short* Kb = K  + (size_t)bh * 4096 * 64;
    const unsigned short* Vb = Vt + (size_t)bh * 64 * 4096;

    bf16x8 bqa[4], bqb[4];
    #pragma unroll
    for (int dsub = 0; dsub < 4; dsub++){
        bqa[dsub] = *(const bf16x8*)(Qb + (size_t)(q0 + ln)*64      + dsub*16 + hi*8);
        bqb[dsub] = *(const bf16x8*)(Qb + (size_t)(q0 + 32 + ln)*64 + dsub*16 + hi*8);
    }

    int srow = lane >> 3;
    int sswz = (lane & 7) ^ srow;

    auto stageK = [&](int kt){
        int kv0 = kt * 64;
        unsigned short* dst = &Kl[kt & 1][0];
        #pragma unroll
        for (int i = 0; i < 4; i++){
            int r0 = w*32 + i*8;
            gload16(Kb + (size_t)(kv0 + r0 + srow)*64 + sswz*8, dst + r0*64);
        }
    };

    // V fragment base: lane (ln,hi) reads d=ln (and d=32+ln), kv = kt*64 + w*32 + hi*8 (+16 for hsel1)
    const unsigned short* Vbase = Vb + (size_t)ln*4096 + w*32 + hi*8;

    f32x16 o0a, o1a, o0b, o1b, z, sEA, sEB, sOA, sOB;
    #pragma unroll
    for (int r = 0; r < 16; r++){ o0a[r]=0.f; o1a[r]=0.f; o0b[r]=0.f; o1b[r]=0.f; z[r]=0.f; }
    float lsA = 0.f, lsB = 0.f;
    bf16x8 Ve0, Ve1, Ve2, Ve3, Vo0, Vo1, Vo2, Vo3;

    const char* KbA = (const char*)&Kl[0][0] + (w*32 + ln)*128;
    int swzr = (ln & 7) << 4;

#define VLOAD(V0,V1,V2,V3, kt) { \
    const unsigned short* vp = Vbase + (size_t)(kt)*64; \
    V0 = *(const bf16x8*)(vp); \
    V1 = *(const bf16x8*)(vp + (size_t)32*4096); \
    V2 = *(const bf16x8*)(vp + 16); \
    V3 = *(const bf16x8*)(vp + 16 + (size_t)32*4096); }

#define QKSTEP(SA,SB, BOFF) { \
    { int cb = (hi*16) ^ swzr; \
      bf16x8 ak = *(const bf16x8*)(KbA + (BOFF) + cb); \
      SA = MFMA32(ak, bqa[0], z); \
      SB = MFMA32(ak, bqb[0], z); } \
    _Pragma("unroll") \
    for (int dsub = 1; dsub < 4; dsub++){ \
        int cb = (dsub*32 + hi*16) ^ swzr; \
        bf16x8 ak = *(const bf16x8*)(KbA + (BOFF) + cb); \
        SA = MFMA32(ak, bqa[dsub], SA); \
        SB = MFMA32(ak, bqb[dsub], SB); \
    } }

#define FINISH(SA,SB, V0,V1,V2,V3) { \
    _Pragma("unroll") \
    for (int r = 0; r < 16; r++){ SA[r] = __builtin_amdgcn_exp2f(SA[r]); lsA += SA[r]; } \
    _Pragma("unroll") \
    for (int r = 0; r < 16; r++){ SB[r] = __builtin_amdgcn_exp2f(SB[r]); lsB += SB[r]; } \
    _Pragma("unroll") \
    for (int hsel = 0; hsel < 2; hsel++){ \
        int obp = hsel * 8; \
        int a0 = cvtpk(SA[obp+0], SA[obp+1]); \
        int a1 = cvtpk(SA[obp+2], SA[obp+3]); \
        int c0 = cvtpk(SA[obp+4], SA[obp+5]); \
        int c1 = cvtpk(SA[obp+6], SA[obp+7]); \
        plswap(a0, c0); plswap(a1, c1); \
        union { int i[4]; bf16x8 v; } fuA; \
        fuA.i[0] = a0; fuA.i[1] = a1; fuA.i[2] = c0; fuA.i[3] = c1; \
        int d0 = cvtpk(SB[obp+0], SB[obp+1]); \
        int d1 = cvtpk(SB[obp+2], SB[obp+3]); \
        int e0 = cvtpk(SB[obp+4], SB[obp+5]); \
        int e1 = cvtpk(SB[obp+6], SB[obp+7]); \
        plswap(d0, e0); plswap(d1, e1); \
        union { int i[4]; bf16x8 v; } fuB; \
        fuB.i[0] = d0; fuB.i[1] = d1; fuB.i[2] = e0; fuB.i[3] = e1; \
        bf16x8 av0 = hsel ? V2 : V0; \
        bf16x8 av1 = hsel ? V3 : V1; \
        o0a = MFMA32(av0, fuA.v, o0a); \
        o1a = MFMA32(av1, fuA.v, o1a); \
        o0b = MFMA32(av0, fuB.v, o0b); \
        o1b = MFMA32(av1, fuB.v, o1b); \
    } }

#define TILETOP() \
    asm volatile("s_waitcnt vmcnt(4)" ::: "memory"); \
    __builtin_amdgcn_s_barrier(); \
    __builtin_amdgcn_sched_barrier(0);

    // prologue
    stageK(0);
    VLOAD(Ve0,Ve1,Ve2,Ve3, 0)

    // iter 0 (even)
    TILETOP()
    stageK(1);
    __builtin_amdgcn_sched_barrier(0);
    QKSTEP(sEA, sEB, 0)
    VLOAD(Vo0,Vo1,Vo2,Vo3, 1)

    // steady pairs: t = 2*tt+1 (odd), 2*tt+2 (even), tt = 0..30  -> t in 1..62
    for (int tt = 0; tt < 31; tt++){
        int t = 2*tt + 1;
        // ---- odd tile t: cur buf1, prev even (Ve = V(t-1))
        TILETOP()
        stageK(t + 1);
        __builtin_amdgcn_sched_barrier(0);
        QKSTEP(sOA, sOB, 64*64*2)
        FINISH(sEA, sEB, Ve0,Ve1,Ve2,Ve3)
        VLOAD(Ve0,Ve1,Ve2,Ve3, t + 1)
        // ---- even tile t+1: cur buf0, prev odd (Vo = V(t))
        TILETOP()
        stageK(t + 2);
        __builtin_amdgcn_sched_barrier(0);
        QKSTEP(sEA, sEB, 0)
        FINISH(sOA, sOB, Vo0,Vo1,Vo2,Vo3)
        VLOAD(Vo0,Vo1,Vo2,Vo3, t + 2)
    }

    // t = 63 (odd): no further staging
    TILETOP()
    QKSTEP(sOA, sOB, 64*64*2)
    FINISH(sEA, sEB, Ve0,Ve1,Ve2,Ve3)
    // finish t = 63
    FINISH(sOA, sOB, Vo0,Vo1,Vo2,Vo3)

#undef VLOAD
#undef QKSTEP
#undef FINISH
#undef TILETOP

    // ---- merge kv-halves via LDS, normalize, store
    lsA += __shfl_xor(lsA, 32);
    lsB += __shfl_xor(lsB, 32);
    __syncthreads();
    if (w == 1){
        #pragma unroll
        for (int r = 0; r < 16; r++){
            mb[r*64 + lane]        = o0a[r];
            mb[1024 + r*64 + lane] = o1a[r];
            mb[2048 + r*64 + lane] = o0b[r];
            mb[3072 + r*64 + lane] = o1b[r];
        }
        if (hi == 0){ mb[4096 + ln] = lsA; mb[4096 + 32 + ln] = lsB; }
    }
    __syncthreads();
    if (w == 0){
        #pragma unroll
        for (int r = 0; r < 16; r++){
            o0a[r] += mb[r*64 + lane];
            o1a[r] += mb[1024 + r*64 + lane];
            o0b[r] += mb[2048 + r*64 + lane];
            o1b[r] += mb[3072 + r*64 + lane];
        }
        float rA = 1.0f / (lsA + mb[4096 + ln]);
        float rB = 1.0f / (lsB + mb[4096 + 32 + ln]);
        int b = bh >> 3, h = bh & 7;
        unsigned short* dstA = O + (size_t)(b*4096 + q0 + ln)*512      + h*64;
        unsigned short* dstB = O + (size_t)(b*4096 + q0 + 32 + ln)*512 + h*64;
        #pragma unroll
        for (int m = 0; m < 2; m++){
            const f32x16& ovA = m ? o1a : o0a;
            const f32x16& ovB = m ? o1b : o0b;
            #pragma unroll
            for (int g = 0; g < 4; g++){
                int d = m*32 + g*8 + hi*4;
                ushort4v pkA, pkB;
                #pragma unroll
                for (int j = 0; j < 4; j++){
                    pkA[j] = f2bf(ovA[g*4 + j] * rA);
                    pkB[j] = f2bf(ovB[g*4 + j] * rB);
                }
                *(ushort4v*)(dstA + d) = pkA;
                *(ushort4v*)(dstB + d) = pkB;
            }
        }
    }
}

// ---------------------------------------------------------------- launch
extern "C" void kernel_launch(void* const* d_in, const int* in_sizes, int n_in,
                              void* d_out, int out_size, void* d_ws, size_t ws_size,
                              hipStream_t stream) {
    const float* q    = (const float*)d_in[0];
    const float* gn_w = (const float*)d_in[1];
    const float* gn_b = (const float*)d_in[2];
    const float* wq   = (const float*)d_in[3];
    const float* bq   = (const float*)d_in[4];
    const float* wk   = (const float*)d_in[5];
    const float* bk   = (const float*)d_in[6];
    const float* wv   = (const float*)d_in[7];
    const float* bv   = (const float*)d_in[8];
    const float* wo   = (const float*)d_in[9];
    const float* bo   = (const float*)d_in[10];
    float* outp = (float*)d_out;

    char* ws = (char*)d_ws;
    float* mean = (float*)ws;
    float* rstd = (float*)(ws + 256);
    unsigned short* xn  = (unsigned short*)(ws + 1024);
    const size_t TOK = (size_t)8192 * 512;
    unsigned short* wqkb = xn + TOK;              // 1024 x 512
    unsigned short* wvb  = wqkb + 1024*512;
    unsigned short* wob  = wvb + 512*512;
    unsigned short* Qb   = wob + 512*512;
    unsigned short* Kb   = Qb + TOK;
    unsigned short* Vt   = Kb + TOK;
    unsigned short* Ob   = Vt + TOK;

    gn_stats<<<64, 256, 0, stream>>>(q, mean, rstd);
    gn_apply<<<dim3(64, 8, 2), 256, 0, stream>>>(q, mean, rstd, gn_w, gn_b, xn);
    wconv<<<dim3(256, 4), 256, 0, stream>>>(wq, wk, wv, wo, wqkb, wvb, wob);
    gemm_qk2<<<dim3(64, 8), 256, 0, stream>>>(xn, wqkb, bq, bk, Qb, Kb);
    gemm_v2<<<dim3(8, 64), 256, 0, stream>>>(wvb, xn, bv, Vt);
    attn6<<<1024, 128, 0, stream>>>(Qb, Kb, Vt, Ob);
    gemm_o2<<<dim3(8, 64), 256, 0, stream>>>(wob, Ob, bo, q, outp);
}

// Round 8
// 156.245 us; speedup vs baseline: 1.1827x; 1.1827x over previous
//
#include <hip/hip_runtime.h>
#include <hip/hip_bf16.h>
#include <cstdint>
#include <cstddef>

using bf16x8   = __attribute__((ext_vector_type(8))) short;
using f32x4    = __attribute__((ext_vector_type(4))) float;
using f32x16   = __attribute__((ext_vector_type(16))) float;
using ushort8  = __attribute__((ext_vector_type(8))) unsigned short;
using ushort4v = __attribute__((ext_vector_type(4))) unsigned short;
using float4v  = __attribute__((ext_vector_type(4))) float;

#define MFMA16(a,b,c) __builtin_amdgcn_mfma_f32_16x16x32_bf16((a),(b),(c),0,0,0)
#define MFMA32(a,b,c) __builtin_amdgcn_mfma_f32_32x32x16_bf16((a),(b),(c),0,0,0)

#define QSCALE 0.18033688011112042f   // log2(e)/8

__device__ __forceinline__ unsigned short f2bf(float f){
    union { float f; unsigned u; } v; v.f = f;
    unsigned r = v.u + 0x7FFFu + ((v.u >> 16) & 1u);
    return (unsigned short)(r >> 16);
}

__device__ __forceinline__ int cvtpk(float lo, float hi){
    int r;
    asm volatile("v_cvt_pk_bf16_f32 %0, %1, %2" : "=v"(r) : "v"(lo), "v"(hi));
    return r;
}

#if __has_builtin(__builtin_amdgcn_permlane32_swap)
__device__ __forceinline__ void plswap(int &a, int &b){
    auto r = __builtin_amdgcn_permlane32_swap(a, b, false, false);
    a = r[0]; b = r[1];
}
#else
__device__ __forceinline__ void plswap(int &a, int &b){
    int ta = __shfl_xor(a, 32), tb = __shfl_xor(b, 32);
    bool hi = ((threadIdx.x & 63) >= 32);
    int na = hi ? tb : a;
    int nb = hi ? b  : ta;
    a = na; b = nb;
}
#endif

__device__ __forceinline__ void gload16(const unsigned short* g, unsigned short* l){
    __builtin_amdgcn_global_load_lds(
        (const __attribute__((address_space(1))) void*)g,
        (__attribute__((address_space(3))) void*)l,
        16, 0, 0);
}

// ---------------------------------------------------------------- gn_stats + wconv merged
// blocks 0-63: GN stats (one per (b,g)); blocks 64-1087: weight fp32->bf16.
__global__ __launch_bounds__(256) void gn_stats_wconv(const float* __restrict__ x,
                                                      float* __restrict__ mean,
                                                      float* __restrict__ rstd,
                                                      const float* __restrict__ w0, const float* __restrict__ w1,
                                                      const float* __restrict__ w2, const float* __restrict__ w3,
                                                      unsigned short* wqk, unsigned short* wv, unsigned short* wo){
    int bid = blockIdx.x;
    if (bid < 64){
        int bg = bid;
        const float4v* p4 = (const float4v*)(x + (size_t)bg * 65536);
        float s = 0.f, ss = 0.f;
        for (int i = threadIdx.x; i < 16384; i += 256){
            float4v v = p4[i];
            s  += v[0]+v[1]+v[2]+v[3];
            ss += v[0]*v[0]+v[1]*v[1]+v[2]*v[2]+v[3]*v[3];
        }
        __shared__ float ls[4], lss[4];
        int lane = threadIdx.x & 63, w = threadIdx.x >> 6;
        #pragma unroll
        for (int o = 32; o > 0; o >>= 1){ s += __shfl_down(s, o); ss += __shfl_down(ss, o); }
        if (lane == 0){ ls[w] = s; lss[w] = ss; }
        __syncthreads();
        if (threadIdx.x == 0){
            float S = ls[0]+ls[1]+ls[2]+ls[3];
            float SS = lss[0]+lss[1]+lss[2]+lss[3];
            float m = S * (1.f/65536.f);
            float var = SS * (1.f/65536.f) - m*m;
            mean[bg] = m;
            rstd[bg] = rsqrtf(var + 1e-5f);
        }
    } else {
        int i2 = bid - 64;
        int y = i2 >> 8, bx = i2 & 255;
        const float* src; unsigned short* dst; float sc = 1.0f;
        switch (y){
            case 0: src = w0; dst = wqk;          sc = QSCALE; break;
            case 1: src = w1; dst = wqk + 512*512; break;
            case 2: src = w2; dst = wv; break;
            default: src = w3; dst = wo; break;
        }
        int i = (bx*256 + threadIdx.x) * 4;
        float4v v = *(const float4v*)(src + i);
        ushort4v o;
        #pragma unroll
        for (int j = 0; j < 4; j++) o[j] = f2bf(v[j]*sc);
        *(ushort4v*)(dst + i) = o;
    }
}

__global__ __launch_bounds__(256) void gn_apply(const float* __restrict__ x,
                                                const float* __restrict__ mean,
                                                const float* __restrict__ rstd,
                                                const float* __restrict__ gw,
                                                const float* __restrict__ gb,
                                                unsigned short* __restrict__ xn){
    int b = blockIdx.z, c0 = blockIdx.y * 64, n0 = blockIdx.x * 64;
    __shared__ unsigned short tile[64][68];
    for (int i = threadIdx.x; i < 64*16; i += 256){
        int row = i >> 4, f4 = i & 15;
        int c = c0 + row;
        int g = b*32 + (c >> 4);
        float rs = rstd[g];
        float wgt = gw[c] * rs;
        float bia = gb[c] - mean[g] * wgt;
        float4v v = *(const float4v*)(x + ((size_t)(b*512 + c))*4096 + n0 + f4*4);
        ushort4v o;
        #pragma unroll
        for (int j = 0; j < 4; j++) o[j] = f2bf(v[j]*wgt + bia);
        *(ushort4v*)&tile[row][f4*4] = o;
    }
    __syncthreads();
    for (int i = threadIdx.x; i < 64*8; i += 256){
        int nr = i >> 3, c8 = i & 7;
        ushort8 o;
        #pragma unroll
        for (int j = 0; j < 8; j++) o[j] = tile[c8*8 + j][nr];
        *(ushort8*)(xn + ((size_t)(b*4096 + n0 + nr))*512 + c0 + c8*8) = o;
    }
}

// ---------------------------------------------------------------- fused QKV projections
// blocks 0-511: QK gemm (BM=128 BN=128); blocks 512-1023: V gemm swapped (BM=64 BN=128).
__global__ __launch_bounds__(256) void gemm_qkv(const unsigned short* __restrict__ xn,
                                                const unsigned short* __restrict__ wqk,
                                                const unsigned short* __restrict__ Wv,
                                                const float* __restrict__ bq,
                                                const float* __restrict__ bk,
                                                const float* __restrict__ bv,
                                                unsigned short* __restrict__ Q,
                                                unsigned short* __restrict__ K,
                                                unsigned short* __restrict__ Vt){
    __shared__ unsigned short Al[128*32];
    __shared__ unsigned short Bl[128*32];
    int bid = blockIdx.x;
    int t = threadIdx.x, lane = t & 63, w = t >> 6;
    int wr = w >> 1, wc = w & 1;
    int lr = lane >> 2, lc = lane & 3;

    if (bid < 512){
        int m0 = (bid & 63) * 128, n0 = (bid >> 6) * 128;
        f32x4 acc[4][4] = {};
        const unsigned short* Asrc = xn  + (size_t)(m0 + w*32 + lr)*512 + lc*8;
        const unsigned short* Bsrc = wqk + (size_t)(n0 + w*32 + lr)*512 + lc*8;
        unsigned short* Adst = &Al[(w*32)*32];
        unsigned short* Bdst = &Bl[(w*32)*32];

        for (int ks = 0; ks < 16; ks++){
            gload16(Asrc + ks*32,          Adst);
            gload16(Asrc + ks*32 + 16*512, Adst + 16*32);
            gload16(Bsrc + ks*32,          Bdst);
            gload16(Bsrc + ks*32 + 16*512, Bdst + 16*32);
            asm volatile("s_waitcnt vmcnt(0)" ::: "memory");
            __syncthreads();
            bf16x8 a[4], b[4];
            #pragma unroll
            for (int mi = 0; mi < 4; mi++) a[mi] = *(bf16x8*)&Al[(wr*64 + mi*16 + (lane&15))*32 + (lane>>4)*8];
            #pragma unroll
            for (int ni = 0; ni < 4; ni++) b[ni] = *(bf16x8*)&Bl[(wc*64 + ni*16 + (lane&15))*32 + (lane>>4)*8];
            #pragma unroll
            for (int mi = 0; mi < 4; mi++)
                #pragma unroll
                for (int ni = 0; ni < 4; ni++)
                    acc[mi][ni] = MFMA16(a[mi], b[ni], acc[mi][ni]);
            __syncthreads();
        }

        int cK = n0 >> 9;
        const float* bias = cK ? bk : bq;
        unsigned short* dst0 = cK ? K : Q;
        float bsc = cK ? 1.0f : QSCALE;
        #pragma unroll
        for (int mi = 0; mi < 4; mi++)
            #pragma unroll
            for (int ni = 0; ni < 4; ni++)
                #pragma unroll
                for (int r = 0; r < 4; r++){
                    int mrow = m0 + wr*64 + mi*16 + (lane>>4)*4 + r;
                    int col  = (n0 & 511) + wc*64 + ni*16 + (lane&15);
                    int b_ = mrow >> 12, n = mrow & 4095;
                    int h = col >> 6, d = col & 63;
                    float v = acc[mi][ni][r] + bias[col]*bsc;
                    dst0[(size_t)((b_*8+h)*4096 + n)*64 + d] = f2bf(v);
                }
    } else {
        int i2 = bid - 512;
        int m0 = (i2 & 7) * 64, n0 = (i2 >> 3) * 128;
        f32x4 acc[2][4] = {};
        const unsigned short* Asrc = Wv + (size_t)(m0 + w*16 + lr)*512 + lc*8;
        const unsigned short* Bsrc = xn + (size_t)(n0 + w*32 + lr)*512 + lc*8;
        unsigned short* Adst = &Al[(w*16)*32];
        unsigned short* Bdst = &Bl[(w*32)*32];

        for (int ks = 0; ks < 16; ks++){
            gload16(Asrc + ks*32,          Adst);
            gload16(Bsrc + ks*32,          Bdst);
            gload16(Bsrc + ks*32 + 16*512, Bdst + 16*32);
            asm volatile("s_waitcnt vmcnt(0)" ::: "memory");
            __syncthreads();
            bf16x8 a[2], b[4];
            #pragma unroll
            for (int mi = 0; mi < 2; mi++) a[mi] = *(bf16x8*)&Al[(wr*32 + mi*16 + (lane&15))*32 + (lane>>4)*8];
            #pragma unroll
            for (int ni = 0; ni < 4; ni++) b[ni] = *(bf16x8*)&Bl[(wc*64 + ni*16 + (lane&15))*32 + (lane>>4)*8];
            #pragma unroll
            for (int mi = 0; mi < 2; mi++)
                #pragma unroll
                for (int ni = 0; ni < 4; ni++)
                    acc[mi][ni] = MFMA16(a[mi], b[ni], acc[mi][ni]);
            __syncthreads();
        }
        #pragma unroll
        for (int mi = 0; mi < 2; mi++)
            #pragma unroll
            for (int ni = 0; ni < 4; ni++)
                #pragma unroll
                for (int r = 0; r < 4; r++){
                    int row  = m0 + wr*32 + mi*16 + (lane>>4)*4 + r;
                    int colm = n0 + wc*64 + ni*16 + (lane&15);
                    int b_ = colm >> 12, n = colm & 4095;
                    int h = row >> 6, d = row & 63;
                    float v = acc[mi][ni][r] + bv[row];
                    Vt[(size_t)((b_*8+h)*64 + d)*4096 + n] = f2bf(v);
                }
    }
}

// ---------------------------------------------------------------- output projection (swapped, m97-style) + residual
__global__ __launch_bounds__(256) void gemm_o2(const unsigned short* __restrict__ Wo,
                                               const unsigned short* __restrict__ Om,
                                               const float* __restrict__ bo,
                                               const float* __restrict__ resid,
                                               float* __restrict__ outp){
    __shared__ unsigned short Al[64*32];
    __shared__ unsigned short Bl[128*32];
    int t = threadIdx.x, lane = t & 63, w = t >> 6;
    int wr = w >> 1, wc = w & 1;
    int m0 = blockIdx.x * 64, n0 = blockIdx.y * 128;
    int lr = lane >> 2, lc = lane & 3;
    f32x4 acc[2][4] = {};

    const unsigned short* Asrc = Wo + (size_t)(m0 + w*16 + lr)*512 + lc*8;
    const unsigned short* Bsrc = Om + (size_t)(n0 + w*32 + lr)*512 + lc*8;
    unsigned short* Adst = &Al[(w*16)*32];
    unsigned short* Bdst = &Bl[(w*32)*32];

    for (int ks = 0; ks < 16; ks++){
        gload16(Asrc + ks*32,          Adst);
        gload16(Bsrc + ks*32,          Bdst);
        gload16(Bsrc + ks*32 + 16*512, Bdst + 16*32);
        asm volatile("s_waitcnt vmcnt(0)" ::: "memory");
        __syncthreads();
        bf16x8 a[2], b[4];
        #pragma unroll
        for (int mi = 0; mi < 2; mi++) a[mi] = *(bf16x8*)&Al[(wr*32 + mi*16 + (lane&15))*32 + (lane>>4)*8];
        #pragma unroll
        for (int ni = 0; ni < 4; ni++) b[ni] = *(bf16x8*)&Bl[(wc*64 + ni*16 + (lane&15))*32 + (lane>>4)*8];
        #pragma unroll
        for (int mi = 0; mi < 2; mi++)
            #pragma unroll
            for (int ni = 0; ni < 4; ni++)
                acc[mi][ni] = MFMA16(a[mi], b[ni], acc[mi][ni]);
        __syncthreads();
    }
    #pragma unroll
    for (int mi = 0; mi < 2; mi++)
        #pragma unroll
        for (int ni = 0; ni < 4; ni++)
            #pragma unroll
            for (int r = 0; r < 4; r++){
                int row  = m0 + wr*32 + mi*16 + (lane>>4)*4 + r;
                int colm = n0 + wc*64 + ni*16 + (lane&15);
                int b_ = colm >> 12, n = colm & 4095;
                size_t oi = ((size_t)(b_*512 + row))*4096 + n;
                outp[oi] = acc[mi][ni][r] + bo[row] + resid[oi];
            }
}

// ---------------------------------------------------------------- flash attention v5 (proven 95us)
__global__ __launch_bounds__(128, 2) void attn5(const unsigned short* __restrict__ Q,
                                                const unsigned short* __restrict__ K,
                                                const unsigned short* __restrict__ Vt,
                                                unsigned short* __restrict__ O){
    int bid = blockIdx.x;
    int idx = bid >> 3;
    int bh = ((bid & 7) << 1) | (idx >> 6);
    int qt = idx & 63;
    int t = threadIdx.x, lane = t & 63, w = t >> 6;   // w = kv-half in {0,1}
    int ln = lane & 31, hi = lane >> 5;
    int q0 = qt * 64;

    __shared__ unsigned short Kl[2][64*64];
    __shared__ unsigned short Vl[2][64*64];

    const unsigned short* Qb = Q  + (size_t)bh * 4096 * 64;
    const unsigned short* Kb = K  + (size_t)bh * 4096 * 64;
    const unsigned short* Vb = Vt + (size_t)bh * 64 * 4096;

    bf16x8 bqa[4], bqb[4];
    #pragma unroll
    for (int dsub = 0; dsub < 4; dsub++){
        bqa[dsub] = *(const bf16x8*)(Qb + (size_t)(q0 + ln)*64      + dsub*16 + hi*8);
        bqb[dsub] = *(const bf16x8*)(Qb + (size_t)(q0 + 32 + ln)*64 + dsub*16 + hi*8);
    }

    int srow = lane >> 3;
    int sswz = (lane & 7) ^ srow;

    auto stage = [&](int buf, int kt){
        int kv0 = kt * 64;
        #pragma unroll
        for (int i = 0; i < 4; i++){
            int r0 = w*32 + i*8;
            gload16(Kb + (size_t)(kv0 + r0 + srow)*64 + sswz*8, &Kl[buf][r0*64]);
        }
        #pragma unroll
        for (int i = 0; i < 4; i++){
            int r0 = w*32 + i*8;
            gload16(Vb + (size_t)(r0 + srow)*4096 + kv0 + sswz*8, &Vl[buf][r0*64]);
        }
    };

    stage(0, 0);

    f32x16 o0a, o1a, o0b, o1b, z;
    #pragma unroll
    for (int r = 0; r < 16; r++){ o0a[r]=0.f; o1a[r]=0.f; o0b[r]=0.f; o1b[r]=0.f; z[r]=0.f; }
    float lsA = 0.f, lsB = 0.f;

    const char* KbA = (const char*)&Kl[0][0] + (w*32 + ln)*128;
    const char* VbA = (const char*)&Vl[0][0] + ln*128;
    int swzr = (ln & 7) << 4;

    for (int kt = 0; kt < 64; kt++){
        asm volatile("s_waitcnt vmcnt(0)" ::: "memory");
        __builtin_amdgcn_s_barrier();
        __builtin_amdgcn_sched_barrier(0);
        if (kt < 63) stage((kt + 1) & 1, kt + 1);
        __builtin_amdgcn_sched_barrier(0);

        int boff = (kt & 1) * (64*64*2);

        f32x16 sA, sB;
        {
            int cb = (hi*16) ^ swzr;
            bf16x8 ak = *(const bf16x8*)(KbA + boff + cb);
            sA = MFMA32(ak, bqa[0], z);
            sB = MFMA32(ak, bqb[0], z);
        }
        __builtin_amdgcn_s_setprio(1);
        #pragma unroll
        for (int dsub = 1; dsub < 4; dsub++){
            int cb = (dsub*32 + hi*16) ^ swzr;
            bf16x8 ak = *(const bf16x8*)(KbA + boff + cb);
            sA = MFMA32(ak, bqa[dsub], sA);
            sB = MFMA32(ak, bqb[dsub], sB);
        }
        __builtin_amdgcn_s_setprio(0);

        #pragma unroll
        for (int r = 0; r < 16; r++){ sA[r] = __builtin_amdgcn_exp2f(sA[r]); lsA += sA[r]; }
        #pragma unroll
        for (int r = 0; r < 16; r++){ sB[r] = __builtin_amdgcn_exp2f(sB[r]); lsB += sB[r]; }

        __builtin_amdgcn_s_setprio(1);
        #pragma unroll
        for (int hsel = 0; hsel < 2; hsel++){
            int obp = hsel * 8;
            int a0 = cvtpk(sA[obp+0], sA[obp+1]);
            int a1 = cvtpk(sA[obp+2], sA[obp+3]);
            int c0 = cvtpk(sA[obp+4], sA[obp+5]);
            int c1 = cvtpk(sA[obp+6], sA[obp+7]);
            plswap(a0, c0);
            plswap(a1, c1);
            union { int i[4]; bf16x8 v; } fuA;
            fuA.i[0] = a0; fuA.i[1] = a1; fuA.i[2] = c0; fuA.i[3] = c1;

            int d0 = cvtpk(sB[obp+0], sB[obp+1]);
            int d1 = cvtpk(sB[obp+2], sB[obp+3]);
            int e0 = cvtpk(sB[obp+4], sB[obp+5]);
            int e1 = cvtpk(sB[obp+6], sB[obp+7]);
            plswap(d0, e0);
            plswap(d1, e1);
            union { int i[4]; bf16x8 v; } fuB;
            fuB.i[0] = d0; fuB.i[1] = d1; fuB.i[2] = e0; fuB.i[3] = e1;

            int cb = ((w*4 + hsel*2 + hi) << 4) ^ swzr;
            bf16x8 av0 = *(const bf16x8*)(VbA + boff + cb);
            bf16x8 av1 = *(const bf16x8*)(VbA + boff + 32*128 + cb);
            o0a = MFMA32(av0, fuA.v, o0a);
            o1a = MFMA32(av1, fuA.v, o1a);
            o0b = MFMA32(av0, fuB.v, o0b);
            o1b = MFMA32(av1, fuB.v, o1b);
        }
        __builtin_amdgcn_s_setprio(0);
    }

    lsA += __shfl_xor(lsA, 32);
    lsB += __shfl_xor(lsB, 32);
    __syncthreads();
    float* m1 = (float*)&Kl[0][0];
    float* m2 = (float*)&Vl[0][0];
    if (w == 1){
        #pragma unroll
        for (int r = 0; r < 16; r++){
            m1[r*64 + lane]        = o0a[r];
            m1[1024 + r*64 + lane] = o1a[r];
            m2[r*64 + lane]        = o0b[r];
            m2[1024 + r*64 + lane] = o1b[r];
        }
        if (hi == 0){ m2[2048 + ln] = lsA; m2[2048 + 32 + ln] = lsB; }
    }
    __syncthreads();
    if (w == 0){
        #pragma unroll
        for (int r = 0; r < 16; r++){
            o0a[r] += m1[r*64 + lane];
            o1a[r] += m1[1024 + r*64 + lane];
            o0b[r] += m2[r*64 + lane];
            o1b[r] += m2[1024 + r*64 + lane];
        }
        float rA = 1.0f / (lsA + m2[2048 + ln]);
        float rB = 1.0f / (lsB + m2[2048 + 32 + ln]);
        int b = bh >> 3, h = bh & 7;
        unsigned short* dstA = O + (size_t)(b*4096 + q0 + ln)*512      + h*64;
        unsigned short* dstB = O + (size_t)(b*4096 + q0 + 32 + ln)*512 + h*64;
        #pragma unroll
        for (int m = 0; m < 2; m++){
            const f32x16& ovA = m ? o1a : o0a;
            const f32x16& ovB = m ? o1b : o0b;
            #pragma unroll
            for (int g = 0; g < 4; g++){
                int d = m*32 + g*8 + hi*4;
                ushort4v pkA, pkB;
                #pragma unroll
                for (int j = 0; j < 4; j++){
                    pkA[j] = f2bf(ovA[g*4 + j] * rA);
                    pkB[j] = f2bf(ovB[g*4 + j] * rB);
                }
                *(ushort4v*)(dstA + d) = pkA;
                *(ushort4v*)(dstB + d) = pkB;
            }
        }
    }
}

// ---------------------------------------------------------------- launch
extern "C" void kernel_launch(void* const* d_in, const int* in_sizes, int n_in,
                              void* d_out, int out_size, void* d_ws, size_t ws_size,
                              hipStream_t stream) {
    const float* q    = (const float*)d_in[0];
    const float* gn_w = (const float*)d_in[1];
    const float* gn_b = (const float*)d_in[2];
    const float* wq   = (const float*)d_in[3];
    const float* bq   = (const float*)d_in[4];
    const float* wk   = (const float*)d_in[5];
    const float* bk   = (const float*)d_in[6];
    const float* wv   = (const float*)d_in[7];
    const float* bv   = (const float*)d_in[8];
    const float* wo   = (const float*)d_in[9];
    const float* bo   = (const float*)d_in[10];
    float* outp = (float*)d_out;

    char* ws = (char*)d_ws;
    float* mean = (float*)ws;
    float* rstd = (float*)(ws + 256);
    unsigned short* xn  = (unsigned short*)(ws + 1024);
    const size_t TOK = (size_t)8192 * 512;
    unsigned short* wqkb = xn + TOK;              // 1024 x 512
    unsigned short* wvb  = wqkb + 1024*512;
    unsigned short* wob  = wvb + 512*512;
    unsigned short* Qb   = wob + 512*512;
    unsigned short* Kb   = Qb + TOK;
    unsigned short* Vt   = Kb + TOK;
    unsigned short* Ob   = Vt + TOK;

    gn_stats_wconv<<<1088, 256, 0, stream>>>(q, mean, rstd, wq, wk, wv, wo, wqkb, wvb, wob);
    gn_apply<<<dim3(64, 8, 2), 256, 0, stream>>>(q, mean, rstd, gn_w, gn_b, xn);
    gemm_qkv<<<1024, 256, 0, stream>>>(xn, wqkb, wvb, bq, bk, bv, Qb, Kb, Vt);
    attn5<<<1024, 128, 0, stream>>>(Qb, Kb, Vt, Ob);
    gemm_o2<<<dim3(8, 64), 256, 0, stream>>>(wob, Ob, bo, q, outp);
}